// Round 2
// baseline (1316.548 us; speedup 1.0000x reference)
//
#include <hip/hip_runtime.h>
#include <hip/hip_bf16.h>

typedef __attribute__((ext_vector_type(8))) short short8;
typedef __attribute__((ext_vector_type(4))) float f32x4;

constexpr int S_DIM  = 1024;
constexpr int IN_DIM = 4096;
constexpr int OUT_DIM = 4096;
constexpr int TM = 128;
constexpr int TN = 128;
constexpr int TK = 64;

__device__ __forceinline__ unsigned int bf2pk(float a, float b) {
    union { __hip_bfloat16 h; unsigned short u; } ca, cb;
    ca.h = __float2bfloat16(a);
    cb.h = __float2bfloat16(b);
    return (unsigned int)ca.u | ((unsigned int)cb.u << 16);
}

__global__ __launch_bounds__(256, 2)
void mlora_gemm(const float* __restrict__ x, const int* __restrict__ aids,
                const float* __restrict__ w, float* __restrict__ out) {
    // bf16 tiles in LDS, row stride 128 B, XOR-swizzled at 16B granularity
    __shared__ __align__(16) unsigned char As[TM * TK * 2];  // [m][k] 16 KB
    __shared__ __align__(16) unsigned char Bs[TN * TK * 2];  // [n][k] 16 KB

    const int tid  = threadIdx.x;
    const int lane = tid & 63;
    const int wid  = tid >> 6;
    const int bn0  = blockIdx.x * TN;
    const int bm0  = blockIdx.y * TM;
    const int bb   = blockIdx.z;
    const int aid  = aids[bb];

    const float* Abase = x + ((size_t)bb * S_DIM + bm0) * IN_DIM;
    const float* Bbase = w + (size_t)aid * IN_DIM * OUT_DIM + bn0;

    // wave -> 64x64 sub-tile: 2x2 wave grid
    const int wr = (wid >> 1) * 64;   // m offset inside tile
    const int wc = (wid & 1) * 64;    // n offset inside tile

    f32x4 acc[4][4] = {};

    // A staging: pass p covers row = p*16 + (tid>>4); float4 at k-offset (tid&15)*4
    const int a_row4 = tid >> 4;
    const int a_k    = (tid & 15) * 4;
    // B staging: column n = tid&127, k-groups start at (tid>>7)*8 (+ g*16)
    const int b_n  = tid & 127;
    const int b_k0 = (tid >> 7) * 8;

    const int l15 = lane & 15;
    const int lk  = lane >> 4;

    for (int k0 = 0; k0 < IN_DIM; k0 += TK) {
        // ---- stage A: [TM][TK] fp32 -> bf16, coalesced float4 loads along k ----
        #pragma unroll
        for (int p = 0; p < 8; ++p) {
            const int row = p * 16 + a_row4;
            f32x4 v = *reinterpret_cast<const f32x4*>(Abase + (size_t)row * IN_DIM + (k0 + a_k));
            uint2 d;
            d.x = bf2pk(v[0], v[1]);
            d.y = bf2pk(v[2], v[3]);
            const int off = row * (TK * 2) + ((a_k * 2) ^ ((row & 7) << 4));
            *reinterpret_cast<uint2*>(&As[off]) = d;
        }
        // ---- stage B transposed: gather 8 k per n (loads coalesced along n) ----
        {
            const float* bp = Bbase + (size_t)(k0 + b_k0) * OUT_DIM + b_n;
            #pragma unroll
            for (int g = 0; g < 4; ++g) {
                float f0 = bp[(size_t)(g * 16 + 0) * OUT_DIM];
                float f1 = bp[(size_t)(g * 16 + 1) * OUT_DIM];
                float f2 = bp[(size_t)(g * 16 + 2) * OUT_DIM];
                float f3 = bp[(size_t)(g * 16 + 3) * OUT_DIM];
                float f4 = bp[(size_t)(g * 16 + 4) * OUT_DIM];
                float f5 = bp[(size_t)(g * 16 + 5) * OUT_DIM];
                float f6 = bp[(size_t)(g * 16 + 6) * OUT_DIM];
                float f7 = bp[(size_t)(g * 16 + 7) * OUT_DIM];
                uint4 d;
                d.x = bf2pk(f0, f1);
                d.y = bf2pk(f2, f3);
                d.z = bf2pk(f4, f5);
                d.w = bf2pk(f6, f7);
                const int ks = b_k0 + g * 16;
                const int off = b_n * (TK * 2) + ((ks * 2) ^ ((b_n & 7) << 4));
                *reinterpret_cast<uint4*>(&Bs[off]) = d;
            }
        }
        __syncthreads();

        // ---- compute: 2 k-chunks of 32, 4x4 fragments per wave ----
        #pragma unroll
        for (int kc = 0; kc < 2; ++kc) {
            const int kbyte = kc * 64 + lk * 16;
            short8 af[4], bfr[4];
            #pragma unroll
            for (int m = 0; m < 4; ++m) {
                const int row = wr + m * 16 + l15;
                af[m] = *reinterpret_cast<const short8*>(&As[row * (TK * 2) + (kbyte ^ ((row & 7) << 4))]);
            }
            #pragma unroll
            for (int n = 0; n < 4; ++n) {
                const int row = wc + n * 16 + l15;
                bfr[n] = *reinterpret_cast<const short8*>(&Bs[row * (TK * 2) + (kbyte ^ ((row & 7) << 4))]);
            }
            #pragma unroll
            for (int m = 0; m < 4; ++m) {
                #pragma unroll
                for (int n = 0; n < 4; ++n) {
                    acc[m][n] = __builtin_amdgcn_mfma_f32_16x16x32_bf16(af[m], bfr[n], acc[m][n], 0, 0, 0);
                }
            }
        }
        __syncthreads();
    }

    // ---- epilogue: D layout col=lane&15, row=(lane>>4)*4+reg ----
    float* obase = out + ((size_t)bb * S_DIM + bm0 + wr) * OUT_DIM + bn0 + wc;
    #pragma unroll
    for (int m = 0; m < 4; ++m) {
        #pragma unroll
        for (int n = 0; n < 4; ++n) {
            const int col = n * 16 + l15;
            #pragma unroll
            for (int r = 0; r < 4; ++r) {
                obase[(size_t)(m * 16 + lk * 4 + r) * OUT_DIM + col] = acc[m][n][r];
            }
        }
    }
}

extern "C" void kernel_launch(void* const* d_in, const int* in_sizes, int n_in,
                              void* d_out, int out_size, void* d_ws, size_t ws_size,
                              hipStream_t stream) {
    const float* x    = (const float*)d_in[0];
    const int*   aids = (const int*)d_in[1];
    const float* w    = (const float*)d_in[2];
    float* out = (float*)d_out;

    const int nb = in_sizes[1];  // batch = number of adapter ids (8)
    dim3 grid(OUT_DIM / TN, S_DIM / TM, nb);
    dim3 block(256);
    mlora_gemm<<<grid, block, 0, stream>>>(x, aids, w, out);
}

// Round 3
// 478.017 us; speedup vs baseline: 2.7542x; 2.7542x over previous
//
#include <hip/hip_runtime.h>
#include <hip/hip_bf16.h>

typedef __attribute__((ext_vector_type(8))) short short8;
typedef __attribute__((ext_vector_type(4))) float f32x4;

constexpr int S_DIM   = 1024;
constexpr int IN_DIM  = 4096;   // K
constexpr int OUT_DIM = 4096;   // N
constexpr int NLORA   = 8;
constexpr int TM = 128;
constexpr int TN = 128;
constexpr int TK = 64;

typedef __attribute__((address_space(3))) unsigned char lds_byte_t;
typedef const __attribute__((address_space(1))) unsigned char glb_byte_t;

__device__ __forceinline__ unsigned short f2bf(float a) {
    union { __hip_bfloat16 h; unsigned short u; } c;
    c.h = __float2bfloat16(a);
    return c.u;
}
__device__ __forceinline__ unsigned int bf2pk(float a, float b) {
    return (unsigned int)f2bf(a) | ((unsigned int)f2bf(b) << 16);
}

// ---------------- prep 1: w[a][k][n] fp32 -> wt[a][n][k] bf16 (transposed) ----
__global__ __launch_bounds__(256)
void prep_w(const float* __restrict__ w, unsigned short* __restrict__ wt) {
    __shared__ __align__(16) unsigned short t[64][72];  // stride 144B, 16B-aligned rows
    const int tid = threadIdx.x;
    const int n0 = blockIdx.x * 64;
    const int k0 = blockIdx.y * 64;
    const int a  = blockIdx.z;
    const float* wb = w + (size_t)a * IN_DIM * OUT_DIM;

    const int nl = (tid & 15) * 4;
    #pragma unroll
    for (int p = 0; p < 4; ++p) {
        const int kl = p * 16 + (tid >> 4);
        f32x4 v = *reinterpret_cast<const f32x4*>(wb + (size_t)(k0 + kl) * OUT_DIM + n0 + nl);
        t[nl + 0][kl] = f2bf(v[0]);
        t[nl + 1][kl] = f2bf(v[1]);
        t[nl + 2][kl] = f2bf(v[2]);
        t[nl + 3][kl] = f2bf(v[3]);
    }
    __syncthreads();
    unsigned short* wtb = wt + (size_t)a * IN_DIM * OUT_DIM;
    const int chunk = tid & 7;           // 8 x 16B = one 128B row of 64 bf16
    #pragma unroll
    for (int q = 0; q < 2; ++q) {
        const int row = q * 32 + (tid >> 3);
        uint4 d = *reinterpret_cast<const uint4*>(&t[row][chunk * 8]);
        *reinterpret_cast<uint4*>(wtb + (size_t)(n0 + row) * IN_DIM + k0 + chunk * 8) = d;
    }
}

// ---------------- prep 2: x fp32 -> bf16 ------------------------------------
__global__ __launch_bounds__(256)
void prep_x(const float* __restrict__ x, unsigned short* __restrict__ xb, int n8) {
    const int stride = gridDim.x * blockDim.x;
    for (int i = blockIdx.x * blockDim.x + threadIdx.x; i < n8; i += stride) {
        const size_t o = (size_t)i * 8;
        f32x4 v0 = *reinterpret_cast<const f32x4*>(x + o);
        f32x4 v1 = *reinterpret_cast<const f32x4*>(x + o + 4);
        uint4 d;
        d.x = bf2pk(v0[0], v0[1]);
        d.y = bf2pk(v0[2], v0[3]);
        d.z = bf2pk(v1[0], v1[1]);
        d.w = bf2pk(v1[2], v1[3]);
        *reinterpret_cast<uint4*>(xb + o) = d;
    }
}

// ---------------- main GEMM: m97 structure, bf16, B^T, global_load_lds -------
__global__ __launch_bounds__(256, 2)
void gemm_bt(const unsigned short* __restrict__ xb, const unsigned short* __restrict__ wt,
             const int* __restrict__ aids, float* __restrict__ out, int nwg) {
    __shared__ __align__(16) unsigned char As[TM * TK * 2];  // 16 KB, swizzled content
    __shared__ __align__(16) unsigned char Bs[TN * TK * 2];  // 16 KB

    // T1: XCD-aware swizzle (nwg % 8 == 0). HW bid%8 = XCD -> give each XCD a
    // contiguous chunk of logical tiles (one batch = 256 tiles per XCD at nwg=2048).
    const int bid = blockIdx.x;
    const int cpx = nwg >> 3;
    const int swz = (bid & 7) * cpx + (bid >> 3);
    const int bz = swz >> 8;            // batch
    const int by = (swz & 255) >> 5;    // m-tile (8)
    const int bx = swz & 31;            // n-tile (32)

    const int tid  = threadIdx.x;
    const int lane = tid & 63;
    const int wid  = tid >> 6;
    const int bm0  = by * TM;
    const int bn0  = bx * TN;
    const int aid  = aids[bz];

    const unsigned short* Ab = xb + ((size_t)bz * S_DIM + bm0) * IN_DIM;
    const unsigned short* Bb = wt + (size_t)aid * IN_DIM * OUT_DIM + (size_t)bn0 * IN_DIM;

    const int wr = (wid >> 1) * 64;
    const int wc = (wid & 1) * 64;
    const int l15 = lane & 15;
    const int lk  = lane >> 4;

    // staging geometry: chunk c (0..15) = rows 8c..8c+7, lane l -> row 8c+(l>>3),
    // dest linear (HW: base + l*16). Source k pre-swizzled so that ds_read with
    // byte ^ ((row&7)<<4) retrieves element (row,k): ksrc = ((l&7)^(l>>3))*8 elems.
    const int rl   = lane >> 3;                    // row within chunk / row&7
    const int ksrc = ((lane & 7) ^ rl) << 3;       // elems

    f32x4 acc[4][4] = {};

    for (int k0 = 0; k0 < IN_DIM; k0 += TK) {
        #pragma unroll
        for (int i = 0; i < 4; ++i) {
            const int c = wid * 4 + i;
            const int row = c * 8 + rl;
            __builtin_amdgcn_global_load_lds(
                (glb_byte_t*)(Ab + (size_t)row * IN_DIM + k0 + ksrc),
                (lds_byte_t*)(&As[c * 1024]), 16, 0, 0);
            __builtin_amdgcn_global_load_lds(
                (glb_byte_t*)(Bb + (size_t)row * IN_DIM + k0 + ksrc),
                (lds_byte_t*)(&Bs[c * 1024]), 16, 0, 0);
        }
        __syncthreads();

        #pragma unroll
        for (int kc = 0; kc < 2; ++kc) {
            const int kbyte = kc * 64 + lk * 16;
            short8 af[4], bfr[4];
            #pragma unroll
            for (int m = 0; m < 4; ++m) {
                const int row = wr + m * 16 + l15;
                af[m] = *reinterpret_cast<const short8*>(
                    &As[row * 128 + (kbyte ^ ((row & 7) << 4))]);
            }
            #pragma unroll
            for (int n = 0; n < 4; ++n) {
                const int row = wc + n * 16 + l15;
                bfr[n] = *reinterpret_cast<const short8*>(
                    &Bs[row * 128 + (kbyte ^ ((row & 7) << 4))]);
            }
            #pragma unroll
            for (int m = 0; m < 4; ++m) {
                #pragma unroll
                for (int n = 0; n < 4; ++n) {
                    acc[m][n] = __builtin_amdgcn_mfma_f32_16x16x32_bf16(af[m], bfr[n], acc[m][n], 0, 0, 0);
                }
            }
        }
        __syncthreads();
    }

    float* obase = out + ((size_t)bz * S_DIM + bm0 + wr) * OUT_DIM + bn0 + wc;
    #pragma unroll
    for (int m = 0; m < 4; ++m) {
        #pragma unroll
        for (int n = 0; n < 4; ++n) {
            const int col = n * 16 + l15;
            #pragma unroll
            for (int r = 0; r < 4; ++r) {
                obase[(size_t)(m * 16 + lk * 4 + r) * OUT_DIM + col] = acc[m][n][r];
            }
        }
    }
}

// ---------------- fallback: round-2 fused kernel (passes @1316us) ------------
__global__ __launch_bounds__(256, 2)
void mlora_gemm(const float* __restrict__ x, const int* __restrict__ aids,
                const float* __restrict__ w, float* __restrict__ out) {
    __shared__ __align__(16) unsigned char As[TM * TK * 2];
    __shared__ __align__(16) unsigned char Bs[TN * TK * 2];

    const int tid  = threadIdx.x;
    const int lane = tid & 63;
    const int wid  = tid >> 6;
    const int bn0  = blockIdx.x * TN;
    const int bm0  = blockIdx.y * TM;
    const int bb   = blockIdx.z;
    const int aid  = aids[bb];

    const float* Abase = x + ((size_t)bb * S_DIM + bm0) * IN_DIM;
    const float* Bbase = w + (size_t)aid * IN_DIM * OUT_DIM + bn0;

    const int wr = (wid >> 1) * 64;
    const int wc = (wid & 1) * 64;

    f32x4 acc[4][4] = {};

    const int a_row4 = tid >> 4;
    const int a_k    = (tid & 15) * 4;
    const int b_n  = tid & 127;
    const int b_k0 = (tid >> 7) * 8;
    const int l15 = lane & 15;
    const int lk  = lane >> 4;

    for (int k0 = 0; k0 < IN_DIM; k0 += TK) {
        #pragma unroll
        for (int p = 0; p < 8; ++p) {
            const int row = p * 16 + a_row4;
            f32x4 v = *reinterpret_cast<const f32x4*>(Abase + (size_t)row * IN_DIM + (k0 + a_k));
            uint2 d;
            d.x = bf2pk(v[0], v[1]);
            d.y = bf2pk(v[2], v[3]);
            const int off = row * (TK * 2) + ((a_k * 2) ^ ((row & 7) << 4));
            *reinterpret_cast<uint2*>(&As[off]) = d;
        }
        {
            const float* bp = Bbase + (size_t)(k0 + b_k0) * OUT_DIM + b_n;
            #pragma unroll
            for (int g = 0; g < 4; ++g) {
                float f0 = bp[(size_t)(g * 16 + 0) * OUT_DIM];
                float f1 = bp[(size_t)(g * 16 + 1) * OUT_DIM];
                float f2 = bp[(size_t)(g * 16 + 2) * OUT_DIM];
                float f3 = bp[(size_t)(g * 16 + 3) * OUT_DIM];
                float f4 = bp[(size_t)(g * 16 + 4) * OUT_DIM];
                float f5 = bp[(size_t)(g * 16 + 5) * OUT_DIM];
                float f6 = bp[(size_t)(g * 16 + 6) * OUT_DIM];
                float f7 = bp[(size_t)(g * 16 + 7) * OUT_DIM];
                uint4 d;
                d.x = bf2pk(f0, f1);
                d.y = bf2pk(f2, f3);
                d.z = bf2pk(f4, f5);
                d.w = bf2pk(f6, f7);
                const int ks = b_k0 + g * 16;
                const int off = b_n * (TK * 2) + ((ks * 2) ^ ((b_n & 7) << 4));
                *reinterpret_cast<uint4*>(&Bs[off]) = d;
            }
        }
        __syncthreads();
        #pragma unroll
        for (int kc = 0; kc < 2; ++kc) {
            const int kbyte = kc * 64 + lk * 16;
            short8 af[4], bfr[4];
            #pragma unroll
            for (int m = 0; m < 4; ++m) {
                const int row = wr + m * 16 + l15;
                af[m] = *reinterpret_cast<const short8*>(&As[row * (TK * 2) + (kbyte ^ ((row & 7) << 4))]);
            }
            #pragma unroll
            for (int n = 0; n < 4; ++n) {
                const int row = wc + n * 16 + l15;
                bfr[n] = *reinterpret_cast<const short8*>(&Bs[row * (TK * 2) + (kbyte ^ ((row & 7) << 4))]);
            }
            #pragma unroll
            for (int m = 0; m < 4; ++m) {
                #pragma unroll
                for (int n = 0; n < 4; ++n) {
                    acc[m][n] = __builtin_amdgcn_mfma_f32_16x16x32_bf16(af[m], bfr[n], acc[m][n], 0, 0, 0);
                }
            }
        }
        __syncthreads();
    }

    float* obase = out + ((size_t)bb * S_DIM + bm0 + wr) * OUT_DIM + bn0 + wc;
    #pragma unroll
    for (int m = 0; m < 4; ++m) {
        #pragma unroll
        for (int n = 0; n < 4; ++n) {
            const int col = n * 16 + l15;
            #pragma unroll
            for (int r = 0; r < 4; ++r) {
                obase[(size_t)(m * 16 + lk * 4 + r) * OUT_DIM + col] = acc[m][n][r];
            }
        }
    }
}

extern "C" void kernel_launch(void* const* d_in, const int* in_sizes, int n_in,
                              void* d_out, int out_size, void* d_ws, size_t ws_size,
                              hipStream_t stream) {
    const float* x    = (const float*)d_in[0];
    const int*   aids = (const int*)d_in[1];
    const float* w    = (const float*)d_in[2];
    float* out = (float*)d_out;
    const int nb = in_sizes[1];  // 8

    const size_t WT_BYTES = (size_t)NLORA * IN_DIM * OUT_DIM * 2;   // 256 MiB
    const size_t XB_BYTES = (size_t)nb * S_DIM * IN_DIM * 2;        // 64 MiB

    if (ws_size >= WT_BYTES + XB_BYTES) {
        unsigned short* wt = (unsigned short*)d_ws;
        unsigned short* xbuf = (unsigned short*)((char*)d_ws + WT_BYTES);

        dim3 gw(OUT_DIM / 64, IN_DIM / 64, NLORA);
        prep_w<<<gw, 256, 0, stream>>>(w, wt);

        const int n8 = nb * S_DIM * IN_DIM / 8;
        prep_x<<<2048, 256, 0, stream>>>(x, xbuf, n8);

        const int nwg = nb * (S_DIM / TM) * (OUT_DIM / TN);  // 2048
        gemm_bt<<<nwg, 256, 0, stream>>>(xbuf, wt, aids, out, nwg);
    } else {
        dim3 grid(OUT_DIM / TN, S_DIM / TM, nb);
        mlora_gemm<<<grid, 256, 0, stream>>>(x, aids, w, out);
    }
}

// Round 4
// 463.581 us; speedup vs baseline: 2.8400x; 1.0311x over previous
//
#include <hip/hip_runtime.h>
#include <hip/hip_bf16.h>

typedef __attribute__((ext_vector_type(8))) short short8;
typedef __attribute__((ext_vector_type(4))) float f32x4;

constexpr int S_DIM   = 1024;
constexpr int IN_DIM  = 4096;   // K
constexpr int OUT_DIM = 4096;   // N
constexpr int NLORA   = 8;

typedef __attribute__((address_space(3))) unsigned char lds_byte_t;
typedef const __attribute__((address_space(1))) unsigned char glb_byte_t;

__device__ __forceinline__ unsigned short f2bf(float a) {
    union { __hip_bfloat16 h; unsigned short u; } c;
    c.h = __float2bfloat16(a);
    return c.u;
}
__device__ __forceinline__ unsigned int bf2pk(float a, float b) {
    return (unsigned int)f2bf(a) | ((unsigned int)f2bf(b) << 16);
}

// ---------------- prep 1: w[a][k][n] fp32 -> wt[a][n][k] bf16 (transposed) ----
__global__ __launch_bounds__(256)
void prep_w(const float* __restrict__ w, unsigned short* __restrict__ wt) {
    __shared__ __align__(16) unsigned short t[64][72];
    const int tid = threadIdx.x;
    const int n0 = blockIdx.x * 64;
    const int k0 = blockIdx.y * 64;
    const int a  = blockIdx.z;
    const float* wb = w + (size_t)a * IN_DIM * OUT_DIM;

    const int nl = (tid & 15) * 4;
    #pragma unroll
    for (int p = 0; p < 4; ++p) {
        const int kl = p * 16 + (tid >> 4);
        f32x4 v = *reinterpret_cast<const f32x4*>(wb + (size_t)(k0 + kl) * OUT_DIM + n0 + nl);
        t[nl + 0][kl] = f2bf(v[0]);
        t[nl + 1][kl] = f2bf(v[1]);
        t[nl + 2][kl] = f2bf(v[2]);
        t[nl + 3][kl] = f2bf(v[3]);
    }
    __syncthreads();
    unsigned short* wtb = wt + (size_t)a * IN_DIM * OUT_DIM;
    const int chunk = tid & 7;
    #pragma unroll
    for (int q = 0; q < 2; ++q) {
        const int row = q * 32 + (tid >> 3);
        uint4 d = *reinterpret_cast<const uint4*>(&t[row][chunk * 8]);
        *reinterpret_cast<uint4*>(wtb + (size_t)(n0 + row) * IN_DIM + k0 + chunk * 8) = d;
    }
}

// ---------------- prep 2: x fp32 -> bf16 ------------------------------------
__global__ __launch_bounds__(256)
void prep_x(const float* __restrict__ x, unsigned short* __restrict__ xb, int n8) {
    const int stride = gridDim.x * blockDim.x;
    for (int i = blockIdx.x * blockDim.x + threadIdx.x; i < n8; i += stride) {
        const size_t o = (size_t)i * 8;
        f32x4 v0 = *reinterpret_cast<const f32x4*>(x + o);
        f32x4 v1 = *reinterpret_cast<const f32x4*>(x + o + 4);
        uint4 d;
        d.x = bf2pk(v0[0], v0[1]);
        d.y = bf2pk(v0[2], v0[3]);
        d.z = bf2pk(v1[0], v1[1]);
        d.w = bf2pk(v1[2], v1[3]);
        *reinterpret_cast<uint4*>(xb + o) = d;
    }
}

// ---------------- main GEMM: 256x128 tile, 3-buffer lookahead-2, counted vmcnt
constexpr int BM = 256;
constexpr int BN = 128;
constexpr int BK = 64;
constexpr int NT = IN_DIM / BK;   // 64

__global__ __launch_bounds__(512, 2)
void gemm_p(const unsigned short* __restrict__ xb, const unsigned short* __restrict__ wt,
            const int* __restrict__ aids, float* __restrict__ out) {
    // 3 buffers x (A 32KiB + B 16KiB) = 144 KiB
    __shared__ __align__(16) unsigned char lds[3][49152];

    // T1: XCD swizzle; 1024 wgs, each XCD = 128 consecutive logical tiles = 1 batch
    const int bid = blockIdx.x;
    const int swz = (bid & 7) * 128 + (bid >> 3);
    const int bz  = swz >> 7;           // batch 0..7
    const int rem = swz & 127;
    const int by  = rem >> 5;           // m-tile 0..3
    const int bx  = rem & 31;           // n-tile 0..31

    const int tid  = threadIdx.x;
    const int lane = tid & 63;
    const int wid  = tid >> 6;          // 0..7
    const int bm0  = by * BM;
    const int bn0  = bx * BN;
    const int aid  = aids[bz];

    const unsigned short* Ab = xb + ((size_t)bz * S_DIM + bm0) * IN_DIM;
    const unsigned short* Bb = wt + (size_t)aid * IN_DIM * OUT_DIM + (size_t)bn0 * IN_DIM;

    // 8 waves: 4M x 2N -> per-wave 64x64 output
    const int wr  = (wid >> 1) * 64;
    const int wc  = (wid & 1) * 64;
    const int l15 = lane & 15;
    const int lk  = lane >> 4;

    // staging geometry (verified in round 3): chunk = 8 rows x 128 B (1 KiB),
    // lane l -> row chunk*8 + (l>>3), source k pre-swizzled so ds_read with
    // byte ^ ((row&7)<<4) is conflict-free.
    const int rl   = lane >> 3;
    const int ksrc = ((lane & 7) ^ rl) << 3;     // elements
    const int ca0  = wid * 4;     // A chunks (of 32): 4 per wave
    const int cb0  = wid * 2;     // B chunks (of 16): 2 per wave

    f32x4 acc[4][4] = {};

    // stage half the K-tile's loads (3 per wave): ph=0 -> A chunks 0,1 + B chunk 0
    //                                             ph=1 -> A chunks 2,3 + B chunk 1
    auto stage = [&](int buf, int k0, int ph) {
        const int a0 = ca0 + ph * 2;
        {
            const int row = (a0 + 0) * 8 + rl;
            __builtin_amdgcn_global_load_lds(
                (glb_byte_t*)(Ab + (size_t)row * IN_DIM + k0 + ksrc),
                (lds_byte_t*)(&lds[buf][(a0 + 0) * 1024]), 16, 0, 0);
        }
        {
            const int row = (a0 + 1) * 8 + rl;
            __builtin_amdgcn_global_load_lds(
                (glb_byte_t*)(Ab + (size_t)row * IN_DIM + k0 + ksrc),
                (lds_byte_t*)(&lds[buf][(a0 + 1) * 1024]), 16, 0, 0);
        }
        {
            const int cb = cb0 + ph;
            const int row = cb * 8 + rl;
            __builtin_amdgcn_global_load_lds(
                (glb_byte_t*)(Bb + (size_t)row * IN_DIM + k0 + ksrc),
                (lds_byte_t*)(&lds[buf][32768 + cb * 1024]), 16, 0, 0);
        }
    };

    auto read_frags = [&](int buf, int kc, short8* af, short8* bf) {
        const unsigned char* A = &lds[buf][0];
        const unsigned char* B = &lds[buf][32768];
        const int kbyte = kc * 64 + lk * 16;
        #pragma unroll
        for (int m = 0; m < 4; ++m) {
            const int row = wr + m * 16 + l15;
            af[m] = *reinterpret_cast<const short8*>(&A[row * 128 + (kbyte ^ ((row & 7) << 4))]);
        }
        #pragma unroll
        for (int n = 0; n < 4; ++n) {
            const int row = wc + n * 16 + l15;
            bf[n] = *reinterpret_cast<const short8*>(&B[row * 128 + (kbyte ^ ((row & 7) << 4))]);
        }
    };

    // prologue: fill buffers 0 and 1; wait so that L(0) landed, L(1) in flight
    stage(0, 0, 0);
    stage(0, 0, 1);
    stage(1, BK, 0);
    stage(1, BK, 1);
    asm volatile("s_waitcnt vmcnt(6)" ::: "memory");
    __builtin_amdgcn_sched_barrier(0);
    __builtin_amdgcn_s_barrier();

    int rbuf = 0;
    #pragma unroll 1
    for (int j = 0; j < NT; ++j) {
        const int wbuf = (rbuf >= 1) ? rbuf - 1 : rbuf + 2;   // (j+2)%3
        const int k2 = (j + 2) * BK;
        const bool pre = (j < NT - 2);

        short8 af[4], bf[4];

        // ---- phase 0: kc=0 ----
        read_frags(rbuf, 0, af, bf);
        if (pre) stage(wbuf, k2, 0);
        __builtin_amdgcn_s_barrier();
        __builtin_amdgcn_s_setprio(1);
        #pragma unroll
        for (int m = 0; m < 4; ++m)
            #pragma unroll
            for (int n = 0; n < 4; ++n)
                acc[m][n] = __builtin_amdgcn_mfma_f32_16x16x32_bf16(af[m], bf[n], acc[m][n], 0, 0, 0);
        __builtin_amdgcn_s_setprio(0);
        __builtin_amdgcn_s_barrier();

        // ---- phase 1: kc=1 ----
        read_frags(rbuf, 1, af, bf);
        if (pre) {
            stage(wbuf, k2, 1);
            asm volatile("s_waitcnt vmcnt(6)" ::: "memory");   // keep L(j+2) in flight
        } else {
            asm volatile("s_waitcnt vmcnt(0)" ::: "memory");   // epilogue drain
        }
        __builtin_amdgcn_sched_barrier(0);
        __builtin_amdgcn_s_barrier();
        __builtin_amdgcn_s_setprio(1);
        #pragma unroll
        for (int m = 0; m < 4; ++m)
            #pragma unroll
            for (int n = 0; n < 4; ++n)
                acc[m][n] = __builtin_amdgcn_mfma_f32_16x16x32_bf16(af[m], bf[n], acc[m][n], 0, 0, 0);
        __builtin_amdgcn_s_setprio(0);
        __builtin_amdgcn_s_barrier();

        rbuf = (rbuf == 2) ? 0 : rbuf + 1;
    }

    // ---- epilogue: D layout col=lane&15, row=(lane>>4)*4+reg ----
    float* obase = out + ((size_t)bz * S_DIM + bm0 + wr) * OUT_DIM + bn0 + wc;
    #pragma unroll
    for (int m = 0; m < 4; ++m) {
        #pragma unroll
        for (int n = 0; n < 4; ++n) {
            const int col = n * 16 + l15;
            #pragma unroll
            for (int r = 0; r < 4; ++r) {
                obase[(size_t)(m * 16 + lk * 4 + r) * OUT_DIM + col] = acc[m][n][r];
            }
        }
    }
}

// ---------------- fallback: round-2 fused kernel (passes @1316us) ------------
constexpr int TMf = 128, TNf = 128, TKf = 64;
__global__ __launch_bounds__(256, 2)
void mlora_gemm(const float* __restrict__ x, const int* __restrict__ aids,
                const float* __restrict__ w, float* __restrict__ out) {
    __shared__ __align__(16) unsigned char As[TMf * TKf * 2];
    __shared__ __align__(16) unsigned char Bs[TNf * TKf * 2];

    const int tid  = threadIdx.x;
    const int lane = tid & 63;
    const int wid  = tid >> 6;
    const int bn0  = blockIdx.x * TNf;
    const int bm0  = blockIdx.y * TMf;
    const int bb   = blockIdx.z;
    const int aid  = aids[bb];

    const float* Abase = x + ((size_t)bb * S_DIM + bm0) * IN_DIM;
    const float* Bbase = w + (size_t)aid * IN_DIM * OUT_DIM + bn0;

    const int wr = (wid >> 1) * 64;
    const int wc = (wid & 1) * 64;

    f32x4 acc[4][4] = {};

    const int a_row4 = tid >> 4;
    const int a_k    = (tid & 15) * 4;
    const int b_n  = tid & 127;
    const int b_k0 = (tid >> 7) * 8;
    const int l15 = lane & 15;
    const int lk  = lane >> 4;

    for (int k0 = 0; k0 < IN_DIM; k0 += TKf) {
        #pragma unroll
        for (int p = 0; p < 8; ++p) {
            const int row = p * 16 + a_row4;
            f32x4 v = *reinterpret_cast<const f32x4*>(Abase + (size_t)row * IN_DIM + (k0 + a_k));
            uint2 d;
            d.x = bf2pk(v[0], v[1]);
            d.y = bf2pk(v[2], v[3]);
            const int off = row * (TKf * 2) + ((a_k * 2) ^ ((row & 7) << 4));
            *reinterpret_cast<uint2*>(&As[off]) = d;
        }
        {
            const float* bp = Bbase + (size_t)(k0 + b_k0) * OUT_DIM + b_n;
            #pragma unroll
            for (int g = 0; g < 4; ++g) {
                float f0 = bp[(size_t)(g * 16 + 0) * OUT_DIM];
                float f1 = bp[(size_t)(g * 16 + 1) * OUT_DIM];
                float f2 = bp[(size_t)(g * 16 + 2) * OUT_DIM];
                float f3 = bp[(size_t)(g * 16 + 3) * OUT_DIM];
                float f4 = bp[(size_t)(g * 16 + 4) * OUT_DIM];
                float f5 = bp[(size_t)(g * 16 + 5) * OUT_DIM];
                float f6 = bp[(size_t)(g * 16 + 6) * OUT_DIM];
                float f7 = bp[(size_t)(g * 16 + 7) * OUT_DIM];
                uint4 d;
                d.x = bf2pk(f0, f1);
                d.y = bf2pk(f2, f3);
                d.z = bf2pk(f4, f5);
                d.w = bf2pk(f6, f7);
                const int ks = b_k0 + g * 16;
                const int off = b_n * (TKf * 2) + ((ks * 2) ^ ((b_n & 7) << 4));
                *reinterpret_cast<uint4*>(&Bs[off]) = d;
            }
        }
        __syncthreads();
        #pragma unroll
        for (int kc = 0; kc < 2; ++kc) {
            const int kbyte = kc * 64 + lk * 16;
            short8 af[4], bfr[4];
            #pragma unroll
            for (int m = 0; m < 4; ++m) {
                const int row = wr + m * 16 + l15;
                af[m] = *reinterpret_cast<const short8*>(&As[row * (TKf * 2) + (kbyte ^ ((row & 7) << 4))]);
            }
            #pragma unroll
            for (int n = 0; n < 4; ++n) {
                const int row = wc + n * 16 + l15;
                bfr[n] = *reinterpret_cast<const short8*>(&Bs[row * (TKf * 2) + (kbyte ^ ((row & 7) << 4))]);
            }
            #pragma unroll
            for (int m = 0; m < 4; ++m) {
                #pragma unroll
                for (int n = 0; n < 4; ++n) {
                    acc[m][n] = __builtin_amdgcn_mfma_f32_16x16x32_bf16(af[m], bfr[n], acc[m][n], 0, 0, 0);
                }
            }
        }
        __syncthreads();
    }

    float* obase = out + ((size_t)bb * S_DIM + bm0 + wr) * OUT_DIM + bn0 + wc;
    #pragma unroll
    for (int m = 0; m < 4; ++m) {
        #pragma unroll
        for (int n = 0; n < 4; ++n) {
            const int col = n * 16 + l15;
            #pragma unroll
            for (int r = 0; r < 4; ++r) {
                obase[(size_t)(m * 16 + lk * 4 + r) * OUT_DIM + col] = acc[m][n][r];
            }
        }
    }
}

extern "C" void kernel_launch(void* const* d_in, const int* in_sizes, int n_in,
                              void* d_out, int out_size, void* d_ws, size_t ws_size,
                              hipStream_t stream) {
    const float* x    = (const float*)d_in[0];
    const int*   aids = (const int*)d_in[1];
    const float* w    = (const float*)d_in[2];
    float* out = (float*)d_out;
    const int nb = in_sizes[1];  // 8

    const size_t WT_BYTES = (size_t)NLORA * IN_DIM * OUT_DIM * 2;   // 256 MiB
    const size_t XB_BYTES = (size_t)nb * S_DIM * IN_DIM * 2;        // 64 MiB

    if (ws_size >= WT_BYTES + XB_BYTES) {
        unsigned short* wt = (unsigned short*)d_ws;
        unsigned short* xbuf = (unsigned short*)((char*)d_ws + WT_BYTES);

        dim3 gw(OUT_DIM / 64, IN_DIM / 64, NLORA);
        prep_w<<<gw, 256, 0, stream>>>(w, wt);

        const int n8 = nb * S_DIM * IN_DIM / 8;
        prep_x<<<2048, 256, 0, stream>>>(x, xbuf, n8);

        const int nwg = nb * (S_DIM / BM) * (OUT_DIM / BN);  // 1024
        gemm_p<<<nwg, 512, 0, stream>>>(xbuf, wt, aids, out);
    } else {
        dim3 grid(OUT_DIM / TNf, S_DIM / TMf, nb);
        mlora_gemm<<<grid, 256, 0, stream>>>(x, aids, w, out);
    }
}

// Round 5
// 361.155 us; speedup vs baseline: 3.6454x; 1.2836x over previous
//
#include <hip/hip_runtime.h>
#include <hip/hip_bf16.h>

typedef __attribute__((ext_vector_type(8))) short short8;
typedef __attribute__((ext_vector_type(4))) float f32x4;

constexpr int S_DIM   = 1024;
constexpr int IN_DIM  = 4096;   // K
constexpr int OUT_DIM = 4096;   // N
constexpr int NLORA   = 8;

typedef __attribute__((address_space(3))) unsigned char lds_byte_t;
typedef const __attribute__((address_space(1))) unsigned char glb_byte_t;

__device__ __forceinline__ unsigned short f2bf(float a) {
    union { __hip_bfloat16 h; unsigned short u; } c;
    c.h = __float2bfloat16(a);
    return c.u;
}
__device__ __forceinline__ unsigned int bf2pk(float a, float b) {
    return (unsigned int)f2bf(a) | ((unsigned int)f2bf(b) << 16);
}

// ---- prep 1: w[a][k][n] fp32 -> wt[a][n][k] bf16, only for USED adapters ----
__global__ __launch_bounds__(256)
void prep_w(const float* __restrict__ w, unsigned short* __restrict__ wt,
            const int* __restrict__ aids, int nb) {
    const int a = blockIdx.z;
    bool used = false;
    for (int i = 0; i < nb; ++i) used |= (aids[i] == a);
    if (!used) return;    // uniform per block; wt[a] never read by gemm then

    __shared__ __align__(16) unsigned short t[64][72];
    const int tid = threadIdx.x;
    const int n0 = blockIdx.x * 64;
    const int k0 = blockIdx.y * 64;
    const float* wb = w + (size_t)a * IN_DIM * OUT_DIM;

    const int nl = (tid & 15) * 4;
    #pragma unroll
    for (int p = 0; p < 4; ++p) {
        const int kl = p * 16 + (tid >> 4);
        f32x4 v = *reinterpret_cast<const f32x4*>(wb + (size_t)(k0 + kl) * OUT_DIM + n0 + nl);
        t[nl + 0][kl] = f2bf(v[0]);
        t[nl + 1][kl] = f2bf(v[1]);
        t[nl + 2][kl] = f2bf(v[2]);
        t[nl + 3][kl] = f2bf(v[3]);
    }
    __syncthreads();
    unsigned short* wtb = wt + (size_t)a * IN_DIM * OUT_DIM;
    const int chunk = tid & 7;
    #pragma unroll
    for (int q = 0; q < 2; ++q) {
        const int row = q * 32 + (tid >> 3);
        uint4 d = *reinterpret_cast<const uint4*>(&t[row][chunk * 8]);
        *reinterpret_cast<uint4*>(wtb + (size_t)(n0 + row) * IN_DIM + k0 + chunk * 8) = d;
    }
}

// ---- prep 2: x fp32 -> bf16 -------------------------------------------------
__global__ __launch_bounds__(256)
void prep_x(const float* __restrict__ x, unsigned short* __restrict__ xb, int n8) {
    const int stride = gridDim.x * blockDim.x;
    for (int i = blockIdx.x * blockDim.x + threadIdx.x; i < n8; i += stride) {
        const size_t o = (size_t)i * 8;
        f32x4 v0 = *reinterpret_cast<const f32x4*>(x + o);
        f32x4 v1 = *reinterpret_cast<const f32x4*>(x + o + 4);
        uint4 d;
        d.x = bf2pk(v0[0], v0[1]);
        d.y = bf2pk(v0[2], v0[3]);
        d.z = bf2pk(v1[0], v1[1]);
        d.w = bf2pk(v1[2], v1[3]);
        *reinterpret_cast<uint4*>(xb + o) = d;
    }
}

// ---- main GEMM: 256x256 tile, 4 quadrant-phases/K-tile, counted vmcnt -------
constexpr int BM = 256;
constexpr int BN = 256;
constexpr int BK = 64;
constexpr int NT = IN_DIM / BK;   // 64

__global__ __launch_bounds__(512, 2)
void gemm8p(const unsigned short* __restrict__ xb, const unsigned short* __restrict__ wt,
            const int* __restrict__ aids, float* __restrict__ out) {
    // 2 buffers x (A 32KiB + B 32KiB) = 128 KiB
    __shared__ __align__(16) unsigned char lds[2][65536];

    // T1 XCD swizzle: 512 wgs, 64/XCD = exactly one batch per XCD
    const int bid = blockIdx.x;
    const int swz = (bid & 7) * 64 + (bid >> 3);
    const int bz  = swz >> 6;          // batch 0..7
    const int rem = swz & 63;
    const int by  = rem >> 4;          // m-tile 0..3
    const int bx  = rem & 15;          // n-tile 0..15

    const int tid  = threadIdx.x;
    const int lane = tid & 63;
    const int wid  = tid >> 6;         // 0..7
    const int bm0  = by * BM;
    const int bn0  = bx * BN;
    const int aid  = aids[bz];

    const unsigned short* Ab = xb + ((size_t)bz * S_DIM + bm0) * IN_DIM;
    const unsigned short* Bb = wt + (size_t)aid * IN_DIM * OUT_DIM + (size_t)bn0 * IN_DIM;

    // 8 waves: 2M x 4N -> per-wave 128x64 output
    const int wr  = (wid >> 2) * 128;
    const int wc  = (wid & 3) * 64;
    const int l15 = lane & 15;
    const int lk  = lane >> 4;

    // staging: chunk = 8 rows x 128B (1 KiB), lane l -> row chunk*8 + (l>>3),
    // source k pre-swizzled so ds_read with byte ^ ((row&7)<<4) is conflict-free
    // (verified rounds 3-4: absmax 0.03125, SQ_LDS_BANK_CONFLICT = 0).
    const int rl   = lane >> 3;
    const int ksrc = ((lane & 7) ^ rl) << 3;     // elements

    f32x4 acc[8][4] = {};

    // half h of A (rows h*128..h*128+127): wave stages chunks h*16 + 2*wid + {0,1}
    auto stageA = [&](int buf, int k0, int h) {
        #pragma unroll
        for (int c = 0; c < 2; ++c) {
            const int chunk = h * 16 + wid * 2 + c;
            const int row   = chunk * 8 + rl;
            __builtin_amdgcn_global_load_lds(
                (glb_byte_t*)(Ab + (size_t)row * IN_DIM + k0 + ksrc),
                (lds_byte_t*)(&lds[buf][chunk * 1024]), 16, 0, 0);
        }
    };
    auto stageB = [&](int buf, int k0, int h) {
        #pragma unroll
        for (int c = 0; c < 2; ++c) {
            const int chunk = h * 16 + wid * 2 + c;
            const int row   = chunk * 8 + rl;
            __builtin_amdgcn_global_load_lds(
                (glb_byte_t*)(Bb + (size_t)row * IN_DIM + k0 + ksrc),
                (lds_byte_t*)(&lds[buf][32768 + chunk * 1024]), 16, 0, 0);
        }
    };

    auto readA = [&](int buf, int mh, short8 af[4][2]) {
        #pragma unroll
        for (int i = 0; i < 4; ++i) {
            const int row = wr + mh * 64 + i * 16 + l15;
            #pragma unroll
            for (int kc = 0; kc < 2; ++kc) {
                const int kb = kc * 64 + lk * 16;
                af[i][kc] = *reinterpret_cast<const short8*>(
                    &lds[buf][row * 128 + (kb ^ ((row & 7) << 4))]);
            }
        }
    };
    auto readB = [&](int buf, int np, short8 bf[2][2]) {
        #pragma unroll
        for (int nn = 0; nn < 2; ++nn) {
            const int row = wc + np * 32 + nn * 16 + l15;
            #pragma unroll
            for (int kc = 0; kc < 2; ++kc) {
                const int kb = kc * 64 + lk * 16;
                bf[nn][kc] = *reinterpret_cast<const short8*>(
                    &lds[buf][32768 + row * 128 + (kb ^ ((row & 7) << 4))]);
            }
        }
    };

    auto qmfma = [&](short8 af[4][2], short8 bf[2][2], int mh, int np) {
        __builtin_amdgcn_s_setprio(1);
        #pragma unroll
        for (int i = 0; i < 4; ++i)
            #pragma unroll
            for (int nn = 0; nn < 2; ++nn)
                #pragma unroll
                for (int kc = 0; kc < 2; ++kc)
                    acc[mh * 4 + i][np * 2 + nn] = __builtin_amdgcn_mfma_f32_16x16x32_bf16(
                        af[i][kc], bf[nn][kc], acc[mh * 4 + i][np * 2 + nn], 0, 0, 0);
        __builtin_amdgcn_s_setprio(0);
    };

    // prologue: tile0 -> buf0, tile1 -> buf1; wait tile0 landed (8 in flight)
    stageA(0, 0, 0); stageA(0, 0, 1); stageB(0, 0, 0); stageB(0, 0, 1);
    stageA(1, BK, 0); stageA(1, BK, 1); stageB(1, BK, 0); stageB(1, BK, 1);
    asm volatile("s_waitcnt vmcnt(8)" ::: "memory");
    __builtin_amdgcn_sched_barrier(0);
    __builtin_amdgcn_s_barrier();

    short8 a0[4][2], a1[4][2], b0[2][2], b1[2][2];

    #pragma unroll 1
    for (int j = 0; j < NT; ++j) {
        const int rb = j & 1;                 // read buf; tile j+2 also lands here
        const int k2 = (j + 2) * BK;
        const bool pre = (j < NT - 2);

        // ---- ph0: quadrant (mh0, np0); reads 12 ----
        readA(rb, 0, a0);
        readB(rb, 0, b0);
        __builtin_amdgcn_s_barrier();
        qmfma(a0, b0, 0, 0);
        __builtin_amdgcn_s_barrier();

        // ---- ph1: quadrant (mh0, np1); reads 4 ----
        readB(rb, 1, b1);
        __builtin_amdgcn_s_barrier();
        qmfma(a0, b1, 0, 1);
        __builtin_amdgcn_s_barrier();
        __builtin_amdgcn_sched_barrier(0);    // all B reads of tile j drained here

        // ---- ph2: quadrant (mh1, np1); reads 8; stage B' (tile j+2) ----
        readA(rb, 1, a1);
        if (pre) { stageB(rb, k2, 0); stageB(rb, k2, 1); }
        __builtin_amdgcn_s_barrier();
        qmfma(a1, b1, 1, 1);
        __builtin_amdgcn_s_barrier();
        __builtin_amdgcn_sched_barrier(0);    // all A reads of tile j drained here

        // ---- ph3: quadrant (mh1, np0); reads 0; stage A' (tile j+2) ----
        if (pre) {
            stageA(rb, k2, 0); stageA(rb, k2, 1);
            asm volatile("s_waitcnt vmcnt(8)" ::: "memory");  // tile j+1 landed
        } else if (j == NT - 2) {
            asm volatile("s_waitcnt vmcnt(0)" ::: "memory");  // drain last tile
        }
        __builtin_amdgcn_sched_barrier(0);
        __builtin_amdgcn_s_barrier();
        qmfma(a1, b0, 1, 0);
        __builtin_amdgcn_s_barrier();
    }

    // ---- epilogue: D layout col=lane&15, row=(lane>>4)*4+reg ----
    float* obase = out + ((size_t)bz * S_DIM + bm0 + wr) * OUT_DIM + bn0 + wc;
    #pragma unroll
    for (int m = 0; m < 8; ++m) {
        #pragma unroll
        for (int n = 0; n < 4; ++n) {
            const int col = n * 16 + l15;
            #pragma unroll
            for (int r = 0; r < 4; ++r) {
                obase[(size_t)(m * 16 + lk * 4 + r) * OUT_DIM + col] = acc[m][n][r];
            }
        }
    }
}

// ---- fallback: round-2 fused kernel (passes @1316us) ------------------------
constexpr int TMf = 128, TNf = 128, TKf = 64;
__global__ __launch_bounds__(256, 2)
void mlora_gemm(const float* __restrict__ x, const int* __restrict__ aids,
                const float* __restrict__ w, float* __restrict__ out) {
    __shared__ __align__(16) unsigned char As[TMf * TKf * 2];
    __shared__ __align__(16) unsigned char Bs[TNf * TKf * 2];

    const int tid  = threadIdx.x;
    const int lane = tid & 63;
    const int wid  = tid >> 6;
    const int bn0  = blockIdx.x * TNf;
    const int bm0  = blockIdx.y * TMf;
    const int bb   = blockIdx.z;
    const int aid  = aids[bb];

    const float* Abase = x + ((size_t)bb * S_DIM + bm0) * IN_DIM;
    const float* Bbase = w + (size_t)aid * IN_DIM * OUT_DIM + bn0;

    const int wr = (wid >> 1) * 64;
    const int wc = (wid & 1) * 64;

    f32x4 acc[4][4] = {};

    const int a_row4 = tid >> 4;
    const int a_k    = (tid & 15) * 4;
    const int b_n  = tid & 127;
    const int b_k0 = (tid >> 7) * 8;
    const int l15 = lane & 15;
    const int lk  = lane >> 4;

    for (int k0 = 0; k0 < IN_DIM; k0 += TKf) {
        #pragma unroll
        for (int p = 0; p < 8; ++p) {
            const int row = p * 16 + a_row4;
            f32x4 v = *reinterpret_cast<const f32x4*>(Abase + (size_t)row * IN_DIM + (k0 + a_k));
            uint2 d;
            d.x = bf2pk(v[0], v[1]);
            d.y = bf2pk(v[2], v[3]);
            const int off = row * (TKf * 2) + ((a_k * 2) ^ ((row & 7) << 4));
            *reinterpret_cast<uint2*>(&As[off]) = d;
        }
        {
            const float* bp = Bbase + (size_t)(k0 + b_k0) * OUT_DIM + b_n;
            #pragma unroll
            for (int g = 0; g < 4; ++g) {
                float f0 = bp[(size_t)(g * 16 + 0) * OUT_DIM];
                float f1 = bp[(size_t)(g * 16 + 1) * OUT_DIM];
                float f2 = bp[(size_t)(g * 16 + 2) * OUT_DIM];
                float f3 = bp[(size_t)(g * 16 + 3) * OUT_DIM];
                float f4 = bp[(size_t)(g * 16 + 4) * OUT_DIM];
                float f5 = bp[(size_t)(g * 16 + 5) * OUT_DIM];
                float f6 = bp[(size_t)(g * 16 + 6) * OUT_DIM];
                float f7 = bp[(size_t)(g * 16 + 7) * OUT_DIM];
                uint4 d;
                d.x = bf2pk(f0, f1);
                d.y = bf2pk(f2, f3);
                d.z = bf2pk(f4, f5);
                d.w = bf2pk(f6, f7);
                const int ks = b_k0 + g * 16;
                const int off = b_n * (TKf * 2) + ((ks * 2) ^ ((b_n & 7) << 4));
                *reinterpret_cast<uint4*>(&Bs[off]) = d;
            }
        }
        __syncthreads();
        #pragma unroll
        for (int kc = 0; kc < 2; ++kc) {
            const int kbyte = kc * 64 + lk * 16;
            short8 af[4], bfr[4];
            #pragma unroll
            for (int m = 0; m < 4; ++m) {
                const int row = wr + m * 16 + l15;
                af[m] = *reinterpret_cast<const short8*>(&As[row * (TKf * 2) + (kbyte ^ ((row & 7) << 4))]);
            }
            #pragma unroll
            for (int n = 0; n < 4; ++n) {
                const int row = wc + n * 16 + l15;
                bfr[n] = *reinterpret_cast<const short8*>(&Bs[row * (TKf * 2) + (kbyte ^ ((row & 7) << 4))]);
            }
            #pragma unroll
            for (int m = 0; m < 4; ++m) {
                #pragma unroll
                for (int n = 0; n < 4; ++n) {
                    acc[m][n] = __builtin_amdgcn_mfma_f32_16x16x32_bf16(af[m], bfr[n], acc[m][n], 0, 0, 0);
                }
            }
        }
        __syncthreads();
    }

    float* obase = out + ((size_t)bb * S_DIM + bm0 + wr) * OUT_DIM + bn0 + wc;
    #pragma unroll
    for (int m = 0; m < 4; ++m) {
        #pragma unroll
        for (int n = 0; n < 4; ++n) {
            const int col = n * 16 + l15;
            #pragma unroll
            for (int r = 0; r < 4; ++r) {
                obase[(size_t)(m * 16 + lk * 4 + r) * OUT_DIM + col] = acc[m][n][r];
            }
        }
    }
}

extern "C" void kernel_launch(void* const* d_in, const int* in_sizes, int n_in,
                              void* d_out, int out_size, void* d_ws, size_t ws_size,
                              hipStream_t stream) {
    const float* x    = (const float*)d_in[0];
    const int*   aids = (const int*)d_in[1];
    const float* w    = (const float*)d_in[2];
    float* out = (float*)d_out;
    const int nb = in_sizes[1];  // 8

    const size_t WT_BYTES = (size_t)NLORA * IN_DIM * OUT_DIM * 2;   // 256 MiB
    const size_t XB_BYTES = (size_t)nb * S_DIM * IN_DIM * 2;        // 64 MiB

    if (ws_size >= WT_BYTES + XB_BYTES) {
        unsigned short* wt = (unsigned short*)d_ws;
        unsigned short* xbuf = (unsigned short*)((char*)d_ws + WT_BYTES);

        dim3 gw(OUT_DIM / 64, IN_DIM / 64, NLORA);
        prep_w<<<gw, 256, 0, stream>>>(w, wt, aids, nb);

        const int n8 = nb * S_DIM * IN_DIM / 8;
        prep_x<<<4096, 256, 0, stream>>>(x, xbuf, n8);

        const int nwg = nb * (S_DIM / BM) * (OUT_DIM / BN);  // 512
        gemm8p<<<nwg, 512, 0, stream>>>(xbuf, wt, aids, out);
    } else {
        dim3 grid(OUT_DIM / TNf, S_DIM / TMf, nb);
        mlora_gemm<<<grid, 256, 0, stream>>>(x, aids, w, out);
    }
}